// Round 7
// baseline (73.772 us; speedup 1.0000x reference)
//
#include <hip/hip_runtime.h>
#include <hip/hip_bf16.h>

#define EPS 1e-7f

typedef __attribute__((ext_vector_type(8))) short short8;
typedef __attribute__((ext_vector_type(4))) float f32x4;

// pack two floats to two bf16 (RNE) in one uint (low = first)
__device__ __forceinline__ unsigned pk(float a, float b) {
    __hip_bfloat162 h2 = __float22bfloat162_rn(make_float2(a, b));
    unsigned r; __builtin_memcpy(&r, &h2, 4); return r;
}

__device__ __forceinline__ short8 mk8(float4 f0, float4 f1) {
    uint4 u;
    u.x = pk(f0.x, f0.y); u.y = pk(f0.z, f0.w);
    u.z = pk(f1.x, f1.y); u.w = pk(f1.z, f1.w);
    short8 r; __builtin_memcpy(&r, &u, 16); return r;
}

// ---------------------------------------------------------------------------
// One kernel. Block = 16 batch rows x all 256 m; 512 threads (8 waves).
//   phase 1: A fp32 -> bf16 into LDS, fragment-linear:
//            slot u = (T*8+s)*64 + l holds A[16T+(l&15)][32s+8*(l>>4)+0..7]
//            (global: 16 fully-consumed 128B lines per wave-step;
//             LDS: contiguous b128 writes, conflict-free)
//   phase 2: wave w owns m-tiles {2w, 2w+1}. Per s-step: A-frag from raw y
//            (global, L2-hot), c-frag broadcast, 2 B-frags via ds_read_b128;
//            4 MFMAs (2 dot, 2 A*c).
//   phase 3: cand/min (shfl) -> alpha (block-local) -> z = c + alpha*(y-c).
// ---------------------------------------------------------------------------
__global__ __launch_bounds__(512, 2)
void fused_kernel(const float* __restrict__ y, const float* __restrict__ A,
                  const float* __restrict__ bb, const float* __restrict__ c,
                  float* __restrict__ z)
{
    __shared__ short8 Asw[8192];      // 128 KB bf16 A, fragment-linear
    __shared__ float red[8][16];
    __shared__ float alphas[16];

    const int t    = threadIdx.x;
    const int lane = t & 63;
    const int w    = t >> 6;      // wave id (0..7)
    const int lr   = lane & 15;   // A-frag row (batch) / B-frag col (m)
    const int lg   = lane >> 4;   // k-group
    const int b0   = blockIdx.x * 16;

    // ---- phase 1: convert A into LDS (each thread: 16 slots) ----
    #pragma unroll
    for (int k = 0; k < 16; ++k) {
        const int u = t + 512 * k;
        const int l = u & 63;
        const int s = (u >> 6) & 7;
        const int T = u >> 9;
        const float4* ap =
            (const float4*)(A + (size_t)(16 * T + (l & 15)) * 256 + 32 * s + 8 * (l >> 4));
        Asw[u] = mk8(ap[0], ap[1]);
    }
    __syncthreads();

    // ---- phase 2: MFMA chains ----
    f32x4 acc0  = {0.f,0.f,0.f,0.f};   // A*y, m-tile 2w
    f32x4 acc1  = {0.f,0.f,0.f,0.f};   // A*y, m-tile 2w+1
    f32x4 accc0 = {0.f,0.f,0.f,0.f};   // A*c, m-tile 2w
    f32x4 accc1 = {0.f,0.f,0.f,0.f};   // A*c, m-tile 2w+1

    const int MT0 = 2 * w, MT1 = MT0 + 1;
    const float4* yp = (const float4*)(y + (size_t)(b0 + lr) * 256) + lg * 2;

    #pragma unroll
    for (int s = 0; s < 8; ++s) {
        float4 f0 = yp[8 * s];      // y[b0+lr][32s+8lg .. +3]
        float4 f1 = yp[8 * s + 1];
        short8 af = mk8(f0, f1);
        float4 cv0 = *(const float4*)(c + 32 * s + 8 * lg);
        float4 cv1 = *(const float4*)(c + 32 * s + 8 * lg + 4);
        short8 cf = mk8(cv0, cv1);  // every A-operand row = c
        short8 bf0 = Asw[(MT0 * 8 + s) * 64 + lane];   // contiguous b128
        short8 bf1 = Asw[(MT1 * 8 + s) * 64 + lane];
        acc0  = __builtin_amdgcn_mfma_f32_16x16x32_bf16(af, bf0, acc0,  0, 0, 0);
        acc1  = __builtin_amdgcn_mfma_f32_16x16x32_bf16(af, bf1, acc1,  0, 0, 0);
        accc0 = __builtin_amdgcn_mfma_f32_16x16x32_bf16(cf, bf0, accc0, 0, 0, 0);
        accc1 = __builtin_amdgcn_mfma_f32_16x16x32_bf16(cf, bf1, accc1, 0, 0, 0);
    }

    // ---- phase 3: cand + min (C/D: col m = MT*16+lr, batch row = 4lg+q) ----
    const int m0 = MT0 * 16 + lr;
    const int m1 = MT1 * 16 + lr;
    const float bm0 = bb[m0] - accc0[0];   // A*c rows identical -> [0] valid
    const float bm1 = bb[m1] - accc1[0];

    float cmin[4];
    #pragma unroll
    for (int q = 0; q < 4; ++q) {
        float d0 = acc0[q] - accc0[q];     // A*(y-c)
        float d1 = acc1[q] - accc1[q];
        float ip0 = bm0 / (d0 + EPS);
        float ip1 = bm1 / (d1 + EPS);
        float c0 = (ip0 > 1.f || ip0 < 0.f) ? 2.f : ip0;
        float c1 = (ip1 > 1.f || ip1 < 0.f) ? 2.f : ip1;
        cmin[q] = fminf(c0, c1);
    }
    #pragma unroll
    for (int q = 0; q < 4; ++q) {
        float v = cmin[q];
        v = fminf(v, __shfl_xor(v, 1));
        v = fminf(v, __shfl_xor(v, 2));
        v = fminf(v, __shfl_xor(v, 4));
        v = fminf(v, __shfl_xor(v, 8));
        cmin[q] = v;
    }
    if (lr == 0) {
        #pragma unroll
        for (int q = 0; q < 4; ++q) red[w][lg * 4 + q] = cmin[q];
    }
    __syncthreads();

    if (t < 16) {
        float a = red[0][t];
        #pragma unroll
        for (int i = 1; i < 8; ++i) a = fminf(a, red[i][t]);
        alphas[t] = fminf(a, 1.0f);   // alpha > 1 -> 1
    }
    __syncthreads();

    // epilogue: z = c + alpha*(y - c); 512 thr x 2 = 16 rows x 64 float4
    const float4* y4  = (const float4*)y;
    const float4* c4g = (const float4*)c;
    float4* z4 = (float4*)z;
    #pragma unroll
    for (int k = 0; k < 2; ++k) {
        int pos = t + k * 512;
        int row = pos >> 6, col4 = pos & 63;
        float al  = alphas[row];
        float4 yv = y4[(size_t)(b0 + row) * 64 + col4];
        float4 cv = c4g[col4];
        float4 o;
        o.x = fmaf(al, yv.x - cv.x, cv.x);
        o.y = fmaf(al, yv.y - cv.y, cv.y);
        o.z = fmaf(al, yv.z - cv.z, cv.z);
        o.w = fmaf(al, yv.w - cv.w, cv.w);
        z4[(size_t)(b0 + row) * 64 + col4] = o;
    }
}

extern "C" void kernel_launch(void* const* d_in, const int* in_sizes, int n_in,
                              void* d_out, int out_size, void* d_ws, size_t ws_size,
                              hipStream_t stream) {
    const float* y = (const float*)d_in[0];
    const float* A = (const float*)d_in[1];
    const float* b = (const float*)d_in[2];
    const float* c = (const float*)d_in[3];
    float* z = (float*)d_out;

    const int B = in_sizes[0] / 256;    // 4096
    fused_kernel<<<B / 16, 512, 0, stream>>>(y, A, b, c, z);
}